// Round 7
// baseline (1118.132 us; speedup 1.0000x reference)
//
#include <hip/hip_runtime.h>
#include <hip/hip_bf16.h>
#include <stdint.h>

#define NN 8192
#define DIN 512
#define DOUT 256
#define RB 4  // rows per gemm block

typedef short short8 __attribute__((ext_vector_type(8)));

__device__ __forceinline__ unsigned short f2bf_rne(float x) {
  unsigned u = __float_as_uint(x);
  u += 0x7fffu + ((u >> 16) & 1u);
  return (unsigned short)(u >> 16);
}
__device__ __forceinline__ float bf2f(unsigned short h) {
  return __uint_as_float(((unsigned)h) << 16);
}

// ---- naive fp32 GEMM1: Wh[i][d] = sum_k X[i][k] W[k][d]; Wh1/Wh2 in-block ----
// Correctness-anchor version: no MFMA, no transpose, no shfl, no atomics.
__global__ __launch_bounds__(256) void kt_gemm_naive(const float* __restrict__ X,
                                                     const float* __restrict__ Wg,
                                                     const float* __restrict__ Ab,
                                                     unsigned short* __restrict__ Whb,
                                                     float* __restrict__ Wh1,
                                                     float* __restrict__ Wh2) {
  __shared__ float xs[RB][DIN];        // 8 KB
  __shared__ float red1[RB][256];      // 4 KB
  __shared__ float red2[RB][256];      // 4 KB
  int i0 = blockIdx.x * RB;
  int d = threadIdx.x;
  for (int t = d; t < RB * DIN; t += 256) xs[t >> 9][t & (DIN - 1)] = X[(size_t)i0 * DIN + t];
  __syncthreads();
  float wh[RB] = {0.f, 0.f, 0.f, 0.f};
  for (int k = 0; k < DIN; ++k) {
    float wv = Wg[(size_t)k * DOUT + d];  // coalesced across threads
#pragma unroll
    for (int r = 0; r < RB; ++r) wh[r] = fmaf(xs[r][k], wv, wh[r]);
  }
  float a1 = Ab[d], a2 = Ab[DOUT + d];
#pragma unroll
  for (int r = 0; r < RB; ++r) {
    Whb[(size_t)(i0 + r) * DOUT + d] = f2bf_rne(wh[r]);
    red1[r][d] = wh[r] * a1;
    red2[r][d] = wh[r] * a2;
  }
  __syncthreads();
  for (int s = 128; s > 0; s >>= 1) {
    if (d < s) {
#pragma unroll
      for (int r = 0; r < RB; ++r) {
        red1[r][d] += red1[r][d + s];
        red2[r][d] += red2[r][d + s];
      }
    }
    __syncthreads();
  }
  if (d < RB) {
    Wh1[i0 + d] = red1[d][0];
    Wh2[i0 + d] = red2[d][0];
  }
}

// ---- conservative attention: 8 rows/block, fp32 scores+PV, in-block finalize ----
// Max-free softmax is exact: |score| <= ~10 so exp never overflows; masked
// weights are exactly 0. Output stores are FP32 (the one change vs R6).
__global__ __launch_bounds__(256) void kt_attn_simple(const int* __restrict__ adj,
                                                      const unsigned short* __restrict__ Whb,
                                                      const float* __restrict__ Wh1,
                                                      const float* __restrict__ Wh2,
                                                      float* __restrict__ out) {
  __shared__ __align__(16) unsigned short Whs[64 * DOUT];  // 32 KB: Wh tile [64 j][256 d]
  __shared__ __align__(16) float wlds[64][8];              // weights [j][i]
  __shared__ float lred[8][32];
  __shared__ float lfin[8];
  int tid = threadIdx.x;
  int i0 = blockIdx.x * 8;
  int il = tid & 7, jj = tid >> 3;  // score-phase ownership: row il, j-slots jj, jj+32
  float wh1v = Wh1[i0 + il];
  const int* arow = adj + (size_t)(i0 + il) * NN;
  float acc[8];
#pragma unroll
  for (int i = 0; i < 8; ++i) acc[i] = 0.f;
  float lpart = 0.f;

  for (int j0 = 0; j0 < NN; j0 += 64) {
    __syncthreads();  // previous tile's PV reads complete
    // stage Wh tile: 2048 short8, 8 per thread, fully coalesced
    const short8* src8 = (const short8*)(Whb + (size_t)j0 * DOUT);
    short8* dst8 = (short8*)Whs;
#pragma unroll
    for (int u = 0; u < 8; ++u) dst8[tid + u * 256] = src8[tid + u * 256];
    // scores: 2 weights per thread, pure fp32
    {
      int a1 = arow[j0 + jj];
      int a2 = arow[j0 + 32 + jj];
      float s1 = wh1v + Wh2[j0 + jj];
      float s2 = wh1v + Wh2[j0 + 32 + jj];
      s1 = fmaxf(s1, 0.2f * s1);  // LeakyReLU
      s2 = fmaxf(s2, 0.2f * s2);
      float w1 = (a1 != 0) ? __expf(s1) : 0.f;
      float w2 = (a2 != 0) ? __expf(s2) : 0.f;
      wlds[jj][il] = w1;
      wlds[32 + jj][il] = w2;
      lpart += w1 + w2;
    }
    __syncthreads();
    // PV: thread = output column d; weight float4 reads broadcast (conflict-free)
#pragma unroll 4
    for (int j = 0; j < 64; ++j) {
      float wh = bf2f(Whs[j * DOUT + tid]);
      float4 wa = *(const float4*)&wlds[j][0];
      float4 wb = *(const float4*)&wlds[j][4];
      acc[0] += wa.x * wh;
      acc[1] += wa.y * wh;
      acc[2] += wa.z * wh;
      acc[3] += wa.w * wh;
      acc[4] += wb.x * wh;
      acc[5] += wb.y * wh;
      acc[6] += wb.z * wh;
      acc[7] += wb.w * wh;
    }
  }
  // denominator: sum each row's weights across the 32 jj-owners
  lred[il][jj] = lpart;
  __syncthreads();
  if (tid < 8) {
    float s = 0.f;
#pragma unroll
    for (int m = 0; m < 32; ++m) s += lred[tid][m];
    lfin[tid] = s;
  }
  __syncthreads();
#pragma unroll
  for (int i = 0; i < 8; ++i) {
    float x = acc[i] / lfin[i];
    x = x > 0.f ? x : (__expf(x) - 1.f);  // ELU
    out[(size_t)(i0 + i) * DOUT + tid] = x;  // FP32 store — the R7 change
  }
}

extern "C" void kernel_launch(void* const* d_in, const int* in_sizes, int n_in,
                              void* d_out, int out_size, void* d_ws, size_t ws_size,
                              hipStream_t stream) {
  const float* X = (const float*)d_in[0];       // input fp32 [8192][512]
  const int* adj = (const int*)d_in[1];         // int32 [8192][8192]
  const float* Wg = (const float*)d_in[2];      // weight fp32 [512][256]
  const float* Ab = (const float*)d_in[3];      // a fp32 [512]
  float* out = (float*)d_out;                   // fp32 [8192][256]  <-- was u16/bf16

  // workspace: Wh1 | Wh2 | Whb  (~4.2 MB; all fully written before read)
  char* ws = (char*)d_ws;
  float* Wh1 = (float*)ws;
  size_t off = (size_t)NN * 4;
  float* Wh2 = (float*)(ws + off); off += (size_t)NN * 4;
  unsigned short* Whb = (unsigned short*)(ws + off);
  off += (size_t)NN * DOUT * 2;                              // 4 MB

  kt_gemm_naive<<<NN / RB, 256, 0, stream>>>(X, Wg, Ab, Whb, Wh1, Wh2);
  kt_attn_simple<<<NN / 8, 256, 0, stream>>>(adj, Whb, Wh1, Wh2, out);
}

// Round 10
// 533.257 us; speedup vs baseline: 2.0968x; 2.0968x over previous
//
#include <hip/hip_runtime.h>
#include <hip/hip_bf16.h>
#include <stdint.h>

#define NN 8192
#define DIN 512
#define DOUT 256
#define NSPLIT 4
#define STRIP (NN / NSPLIT) /* 2048 */

typedef short short8 __attribute__((ext_vector_type(8)));
typedef float floatx4 __attribute__((ext_vector_type(4)));

__device__ __forceinline__ unsigned short f2bf_rne(float x) {
  unsigned u = __float_as_uint(x);
  u += 0x7fffu + ((u >> 16) & 1u);
  return (unsigned short)(u >> 16);
}
__device__ __forceinline__ float bf2f(unsigned short h) {
  return __uint_as_float(((unsigned)h) << 16);
}

// -------- weight transpose+cvt: W fp32 [512][256] -> WT bf16 [256][512] --------
__global__ __launch_bounds__(256) void kt_transpose(const float* __restrict__ Wg,
                                                    unsigned short* __restrict__ WT) {
  __shared__ unsigned short sm[32][33];
  int tid = threadIdx.x;
  int bk = blockIdx.x >> 3;  // k tile
  int bn = blockIdx.x & 7;   // n tile
  int k0 = bk * 32, n0 = bn * 32;
  int r = tid >> 3, c4 = (tid & 7) * 4;
  const float* src = Wg + (size_t)(k0 + r) * DOUT + n0 + c4;
#pragma unroll
  for (int x = 0; x < 4; ++x) sm[r][c4 + x] = f2bf_rne(src[x]);
  __syncthreads();
  unsigned short* dst = WT + (size_t)(n0 + r) * DIN + k0 + c4;
#pragma unroll
  for (int x = 0; x < 4; ++x) dst[x] = sm[c4 + x][r];
}

// -- GEMM1 (MFMA): WhT[d][i] = sum_k X[i][k] W[k][d] (X fp32, cvt in-reg);
//    Wh1/Wh2 row dots via shfl + atomicAdd. Computation verified vs R6 anchor. --
__global__ __launch_bounds__(256) void kt_gemm1(const float* __restrict__ X,
                                                const unsigned short* __restrict__ WT,
                                                const float* __restrict__ Ab,
                                                unsigned short* __restrict__ WhT,
                                                float* __restrict__ Wh1,
                                                float* __restrict__ Wh2) {
  int tid = threadIdx.x;
  int w = tid >> 6, lane = tid & 63;
  int col = lane & 15, q = lane >> 4;
  int db = blockIdx.x & 3;   // d block (64 each)
  int ib = blockIdx.x >> 2;  // i block (128 each)
  int i0 = ib * 128;
  int drow = db * 64 + w * 16 + col;  // A row (d), m = lane&15
  const unsigned short* abase = WT + (size_t)drow * DIN + q * 8;
  const float* xbase = X + (size_t)(i0 + col) * DIN + q * 8;
  floatx4 acc[8];
#pragma unroll
  for (int t = 0; t < 8; ++t) acc[t] = (floatx4)(0.0f);
  for (int k0 = 0; k0 < DIN; k0 += 32) {
    short8 af = *(const short8*)(abase + k0);
#pragma unroll
    for (int t = 0; t < 8; ++t) {
      const float* xp = xbase + (size_t)t * 16 * DIN + k0;
      float4 xa = *(const float4*)xp;
      float4 xb = *(const float4*)(xp + 4);
      short8 bf;
      bf[0] = (short)f2bf_rne(xa.x); bf[1] = (short)f2bf_rne(xa.y);
      bf[2] = (short)f2bf_rne(xa.z); bf[3] = (short)f2bf_rne(xa.w);
      bf[4] = (short)f2bf_rne(xb.x); bf[5] = (short)f2bf_rne(xb.y);
      bf[6] = (short)f2bf_rne(xb.z); bf[7] = (short)f2bf_rne(xb.w);
      acc[t] = __builtin_amdgcn_mfma_f32_16x16x32_bf16(af, bf, acc[t], 0, 0, 0);
    }
  }
  // D: col=lane&15 -> i; row=q*4+r -> d
  int dq = db * 64 + w * 16 + q * 4;
  float a1v[4], a2v[4];
#pragma unroll
  for (int r = 0; r < 4; ++r) { a1v[r] = Ab[dq + r]; a2v[r] = Ab[DOUT + dq + r]; }
#pragma unroll
  for (int t = 0; t < 8; ++t) {
    floatx4 v = acc[t];
    int icol = i0 + t * 16 + col;
#pragma unroll
    for (int r = 0; r < 4; ++r) WhT[(size_t)(dq + r) * NN + icol] = f2bf_rne(v[r]);
    float p1 = v[0] * a1v[0] + v[1] * a1v[1] + v[2] * a1v[2] + v[3] * a1v[3];
    float p2 = v[0] * a2v[0] + v[1] * a2v[1] + v[2] * a2v[2] + v[3] * a2v[3];
    p1 += __shfl_xor(p1, 16);
    p1 += __shfl_xor(p1, 32);
    p2 += __shfl_xor(p2, 16);
    p2 += __shfl_xor(p2, 32);
    if (q == 0) {
      atomicAdd(&Wh1[icol], p1);
      atomicAdd(&Wh2[icol], p2);
    }
  }
}

// ---------------- fused masked-softmax attention (rank-1 scores) ----------------
// Max-free softmax is exact: |score| <= ~10, exp can't overflow; masked w = 0.
// P weights rounded to bf16 for MFMA; denominator sums the *rounded* weights.
__device__ __forceinline__ short8 build_a(int4 pa, int4 pb, float wh1, const float* w2,
                                          float& lsum) {
  int av[8] = {pa.x, pa.y, pa.z, pa.w, pb.x, pb.y, pb.z, pb.w};
  short8 af;
#pragma unroll
  for (int e = 0; e < 8; ++e) {
    float sc = wh1 + w2[e];
    sc = fmaxf(sc, 0.2f * sc);  // LeakyReLU
    float ex = __expf(sc);
    float wv = (av[e] != 0) ? ex : 0.0f;
    unsigned short hb = f2bf_rne(wv);
    af[e] = (short)hb;
    lsum += bf2f(hb);
  }
  return af;
}

__global__ __launch_bounds__(256, 2) void kt_attn(const int* __restrict__ adj,
                                                  const unsigned short* __restrict__ WhT,
                                                  const float* __restrict__ Wh1,
                                                  const float* __restrict__ Wh2,
                                                  float* __restrict__ accg,
                                                  float* __restrict__ lg) {
  __shared__ __align__(16) unsigned short tileB[32 * DOUT];  // 16 KB, XOR-swizzled rows
  __shared__ __align__(16) float wh2s[STRIP];                // 8 KB
  int tid = threadIdx.x;
  int w = tid >> 6, lane = tid & 63;
  int col = lane & 15, q = lane >> 4;
  int s = blockIdx.x & (NSPLIT - 1);
  int ib = blockIdx.x / NSPLIT;
  int i0 = ib * 64;
  int jb = s * STRIP;
  int wr = (w >> 1) * 32;   // wave row-group offset (0 or 32)
  int dh = (w & 1) * 128;   // wave d half

  for (int t = tid; t < STRIP / 4; t += 256)
    ((floatx4*)wh2s)[t] = ((const floatx4*)(Wh2 + jb))[t];

  float wh1r0 = Wh1[i0 + wr + col];
  float wh1r1 = Wh1[i0 + wr + 16 + col];

  // staging: thread owns WhT row d = tid; 32-j slice, XOR chunk swizzle
  int drow = tid;
  int fsw = (drow >> 1) & 3;
  const unsigned short* gsrc = WhT + (size_t)drow * NN + jb;
  unsigned short* lrow = &tileB[drow * 32];

  // reader: row d = dh + t*16 + col, j-chunk q at physical chunk q^fc
  int fc = (col >> 1) & 3;
  const unsigned short* bbase = &tileB[(dh + col) * 32 + ((q ^ fc) * 8)];

  const int* aptr0 = adj + ((size_t)(i0 + wr + col) << 13) + jb + q * 8;
  const int* aptr1 = adj + ((size_t)(i0 + wr + 16 + col) << 13) + jb + q * 8;

  floatx4 acc[2][8];
#pragma unroll
  for (int g = 0; g < 2; ++g)
#pragma unroll
    for (int t = 0; t < 8; ++t) acc[g][t] = (floatx4)(0.0f);
  float lp0 = 0.f, lp1 = 0.f;

  // prologue prefetch: tile 0 rows + adj step 0
  short8 st[4];
#pragma unroll
  for (int m = 0; m < 4; ++m) st[m] = *(const short8*)(gsrc + m * 8);
  int4 ad0a = *(const int4*)aptr0;
  int4 ad0b = *(const int4*)(aptr0 + 4);
  int4 ad1a = *(const int4*)aptr1;
  int4 ad1b = *(const int4*)(aptr1 + 4);

  const int NSTEP = STRIP / 32;  // 64
#pragma unroll 1
  for (int k = 0; k < NSTEP; ++k) {
    int jl = k * 32;
    __syncthreads();  // previous step's LDS reads complete
#pragma unroll
    for (int m = 0; m < 4; ++m) *(short8*)(lrow + ((m ^ fsw) * 8)) = st[m];
    __syncthreads();  // tile visible
    if (k + 1 < NSTEP) {
#pragma unroll
      for (int m = 0; m < 4; ++m) st[m] = *(const short8*)(gsrc + (jl + 32) + m * 8);
    }
    short8 bf[8];
#pragma unroll
    for (int t = 0; t < 8; ++t) bf[t] = *(const short8*)(bbase + t * 512);
    floatx4 w2a = *(const floatx4*)&wh2s[jl + q * 8];
    floatx4 w2b = *(const floatx4*)&wh2s[jl + q * 8 + 4];
    float w2[8] = {w2a[0], w2a[1], w2a[2], w2a[3], w2b[0], w2b[1], w2b[2], w2b[3]};
    short8 af0 = build_a(ad0a, ad0b, wh1r0, w2, lp0);
    short8 af1 = build_a(ad1a, ad1b, wh1r1, w2, lp1);
    if (k + 1 < NSTEP) {
      ad0a = *(const int4*)(aptr0 + jl + 32);
      ad0b = *(const int4*)(aptr0 + jl + 36);
      ad1a = *(const int4*)(aptr1 + jl + 32);
      ad1b = *(const int4*)(aptr1 + jl + 36);
    }
#pragma unroll
    for (int t = 0; t < 8; ++t)
      acc[0][t] = __builtin_amdgcn_mfma_f32_16x16x32_bf16(af0, bf[t], acc[0][t], 0, 0, 0);
#pragma unroll
    for (int t = 0; t < 8; ++t)
      acc[1][t] = __builtin_amdgcn_mfma_f32_16x16x32_bf16(af1, bf[t], acc[1][t], 0, 0, 0);
  }

  // l reduction across q groups; one atomic per row per strip (dh=0 waves only)
  lp0 += __shfl_xor(lp0, 16);
  lp0 += __shfl_xor(lp0, 32);
  lp1 += __shfl_xor(lp1, 16);
  lp1 += __shfl_xor(lp1, 32);
  if (((w & 1) == 0) && lane < 16) {
    atomicAdd(&lg[i0 + wr + lane], lp0);
    atomicAdd(&lg[i0 + wr + 16 + lane], lp1);
  }
  // fp32 partial merge via coalesced atomics (4 strips per address)
#pragma unroll
  for (int g = 0; g < 2; ++g) {
#pragma unroll
    for (int t = 0; t < 8; ++t) {
      floatx4 v = acc[g][t];
      int dcol = dh + t * 16 + col;
      int irow = i0 + wr + g * 16 + q * 4;
#pragma unroll
      for (int r = 0; r < 4; ++r) atomicAdd(&accg[(size_t)(irow + r) * DOUT + dcol], v[r]);
    }
  }
}

// ---------------- normalize + ELU -> fp32 out ----------------
__global__ __launch_bounds__(256) void kt_merge(const float* __restrict__ accg,
                                               const float* __restrict__ lg,
                                               float* __restrict__ out) {
  int i = blockIdx.x;
  int d = threadIdx.x;
  size_t idx = (size_t)i * DOUT + d;
  float x = accg[idx] / lg[i];
  x = x > 0.f ? x : (__expf(x) - 1.f);
  out[idx] = x;
}

extern "C" void kernel_launch(void* const* d_in, const int* in_sizes, int n_in,
                              void* d_out, int out_size, void* d_ws, size_t ws_size,
                              hipStream_t stream) {
  const float* X = (const float*)d_in[0];       // input fp32 [8192][512]
  const int* adj = (const int*)d_in[1];         // int32 [8192][8192]
  const float* Wg = (const float*)d_in[2];      // weight fp32 [512][256]
  const float* Ab = (const float*)d_in[3];      // a fp32 [512]
  float* out = (float*)d_out;                   // fp32 [8192][256]

  // workspace: accg | lg | Wh1 | Wh2 | WT | WhT  (~12.4 MB; R3 proved in-bounds)
  char* ws = (char*)d_ws;
  float* accg = (float*)ws;                                  // 8 MB
  size_t off = (size_t)NN * DOUT * 4;
  float* lg = (float*)(ws + off);  off += (size_t)NN * 4;
  float* Wh1 = (float*)(ws + off); off += (size_t)NN * 4;
  float* Wh2 = (float*)(ws + off); off += (size_t)NN * 4;
  size_t zero_bytes = off;                                   // accg+lg+Wh1+Wh2
  unsigned short* WT = (unsigned short*)(ws + off);
  off += (size_t)DOUT * DIN * 2;                             // 256 KB
  unsigned short* WhT = (unsigned short*)(ws + off);
  off += (size_t)DOUT * NN * 2;                              // 4 MB

  hipMemsetAsync(accg, 0, zero_bytes, stream);  // zero atomic accumulators
  kt_transpose<<<128, 256, 0, stream>>>(Wg, WT);
  kt_gemm1<<<256, 256, 0, stream>>>(X, WT, Ab, WhT, Wh1, Wh2);
  kt_attn<<<(NN / 64) * NSPLIT, 256, 0, stream>>>(adj, WhT, Wh1, Wh2, accg, lg);
  kt_merge<<<NN, 256, 0, stream>>>(accg, lg, out);
}